// Round 21
// baseline (200.533 us; speedup 1.0000x reference)
//
#include <hip/hip_runtime.h>
#include <cstdint>
#include <cstddef>

#define NBm 256
#define NAm 96
#define NDm 384
#define NHm 192
#define NFm 96
#define NSm 4
#define NATOMS (NBm*NAm)      /* 24576 */
#define NEe (NATOMS*32)       /* 786432 */
#define CUTOFF_ 5.2f
#define PBLK 256              /* edge-accum blocks = partial copies */
#define EPB (NEe/PBLK)        /* 3072 edges per block */
#define HBLK 96               /* NATOMS/256 hist blocks */
#define MROWS 32              /* k_mlp rows per block (2 waves x 16) */

typedef __attribute__((ext_vector_type(8))) short short8;
typedef __attribute__((ext_vector_type(4))) float float4v;

__device__ __forceinline__ short f2bf(float f){
  union { float f; unsigned u; } v; v.f = f;
  unsigned r = v.u + 0x7FFFu + ((v.u >> 16) & 1u);
  return (short)(r >> 16);
}

// jax.nn.gelu default: tanh approximation
__device__ __forceinline__ float gelu_t(float x){
  float u = 0.7978845608028654f * (x + 0.044715f * x*x*x);
  float e = __expf(-2.0f * fabsf(u));
  float t = (1.0f - e) / (1.0f + e);
  t = (u >= 0.f) ? t : -t;
  return 0.5f * x * (1.0f + t);
}

// ---------- K1: weight prep + per-block species histogram (R14-verified) ----------
#define W1N (NSm*NDm*NHm)   /* 294912 */
#define W2N (NSm*NHm*NFm)   /* 73728 */
#define WNN (NSm*NFm*NFm)   /* 36864 */
#define WTOT (W1N+W2N+WNN)  /* 405504 */
#define WBLK (WTOT/256)     /* 1584 */
// grid = WBLK + HBLK = 1680
__global__ __launch_bounds__(256) void k_prep(
    const float* __restrict__ W1, const float* __restrict__ W2,
    const float* __restrict__ Wn, const int* __restrict__ sp,
    short* __restrict__ W1t, short* __restrict__ W2t, short* __restrict__ Wnt,
    int* __restrict__ Pcnt){
  int b = blockIdx.x;
  if (b < WBLK){
    int idx = b*256 + threadIdx.x;
    if (idx < W1N){
      int s = idx / (NDm*NHm); int rem = idx - s*NDm*NHm;
      int k = rem / NHm, c = rem - k*NHm;
      W1t[(s*NHm + c)*NDm + k] = f2bf(W1[idx]);
    } else if (idx < W1N + W2N){
      int j = idx - W1N;
      int s = j / (NHm*NFm); int rem = j - s*NHm*NFm;
      int k = rem / NFm, c = rem - k*NFm;
      W2t[(s*NFm + c)*NHm + k] = f2bf(W2[j]);
    } else {
      int j = idx - W1N - W2N;
      int s = j / (NFm*NFm); int rem = j - s*NFm*NFm;
      int k = rem / NFm, c = rem - k*NFm;
      Wnt[(s*NFm + c)*NFm + k] = f2bf(Wn[j]);
    }
  } else {
    // per-block species histogram; LDS atomics only, no pre-zero needed
    __shared__ int h[NSm];
    int t = threadIdx.x;
    if (t < NSm) h[t] = 0;
    __syncthreads();
    int i = (b - WBLK)*256 + t;
    atomicAdd(&h[sp[i]], 1);
    __syncthreads();
    if (t < NSm) Pcnt[(b - WBLK)*NSm + t] = h[t];
  }
}

// ---------- K2: redundant-scan ordering (R14-verified) ----------
__global__ __launch_bounds__(256) void k_order(const int* __restrict__ sp,
    const int* __restrict__ Pcnt, int* __restrict__ sps, int* __restrict__ order){
  __shared__ int P[HBLK][NSm];
  __shared__ int stot[NSm], spre[NSm], sscan[NSm+1];
  __shared__ int base[NSm], h[NSm];
  int t = threadIdx.x, b = blockIdx.x;
  if (t < HBLK){
    #pragma unroll
    for (int j=0;j<NSm;j++) P[t][j] = Pcnt[t*NSm + j];
  }
  if (t < NSm) h[t] = 0;
  __syncthreads();
  if (t < NSm){
    int tot = 0, pr = 0;
    for (int bb=0; bb<HBLK; bb++){
      if (bb == b) pr = tot;
      tot += P[bb][t];
    }
    stot[t] = tot; spre[t] = pr;
  }
  __syncthreads();
  if (t == 0){
    int r = 0;
    #pragma unroll
    for (int s2=0;s2<NSm;s2++){ sscan[s2] = r; r += stot[s2]; }
    sscan[NSm] = r;
    if (b == 0){
      #pragma unroll
      for (int s2=0;s2<=NSm;s2++) sps[s2] = sscan[s2];
    }
  }
  __syncthreads();
  if (t < NSm) base[t] = sscan[t] + spre[t];
  __syncthreads();
  int i = b*256 + t;
  int s = sp[i];
  int lr = atomicAdd(&h[s], 1);
  order[base[s] + lr] = i;
}

// ---------- fused MLP: 32-row tiles, 3 co-resident blocks/CU ----------
// Evidence: R20 (1 blk/CU) = 85us, R14 (2 blk/CU) = 41.8us -> co-resident
// blocks overlapping barrier stalls is THE lever. This tile: 128 threads,
// 2 waves x 16 rows, LDS ~46KB -> 3 blocks/CU (grid 768 active = 3/CU).
// Per-wave dataflow byte-identical to R14 (16 rows x full cols, ascending
// K order in every GEMM -> bit-identical accumulation); only stage chunking
// changes: GEMM1 6xK=64 (Ws stride 72), GEMM2 2xK=96 (stride 104), GEMM3 1xK=96.
__global__ __launch_bounds__(128) void k_mlp(
    const float* __restrict__ X, const int* __restrict__ order,
    const int* __restrict__ sps,
    const short* __restrict__ W1t, const short* __restrict__ W2t,
    const short* __restrict__ Wnt, const float* __restrict__ Wf,
    float* __restrict__ pre, float* __restrict__ nd4){
  const int s = blockIdx.y;
  const int s0 = sps[s];
  const int cnt = sps[s+1] - s0;
  const int row0 = blockIdx.x * MROWS;
  if (row0 >= cnt) return;

  __shared__ short Hs[MROWS][200]; // 12.5 KB
  __shared__ short Is[MROWS][104]; // 6.7 KB
  __shared__ short Ws[13824];      // 27.6 KB (192x72); aliased as NL (12.4KB) below
  __shared__ int aids[MROWS];

  const int tid = threadIdx.x;
  if (tid < MROWS){
    int r = row0 + tid;
    aids[tid] = order[s0 + ((r < cnt) ? r : 0)];
  }
  __syncthreads();

  const int wave = tid >> 6, lane = tid & 63;   // wave 0..1
  const int lrow = lane & 15, quad = lane >> 4;
  const int arow = wave*16 + lrow;
  const float* xrow = X + (size_t)aids[arow]*NDm + quad*8;

  // preload & convert all A fragments (GEMM1) up front
  short8 afs[12];
  #pragma unroll
  for (int kb=0; kb<12; kb++){
    const float* p = xrow + kb*32;
    #pragma unroll
    for (int j=0;j<8;j++) afs[kb][j] = f2bf(p[j]);
  }

  // ---- GEMM1: [32,384]@[384,192]; 6 staged chunks of K=64
  const short* W1s = W1t + (size_t)s*NHm*NDm;
  float4v acc[12];
  #pragma unroll
  for (int i=0;i<12;i++){ acc[i][0]=0.f; acc[i][1]=0.f; acc[i][2]=0.f; acc[i][3]=0.f; }
  for (int kc=0; kc<6; kc++){
    __syncthreads();
    for (int e = tid; e < 192*8; e += 128){    // 192 cols x 8 short8 units (K=64)
      int c = e >> 3, u = e & 7;
      *(short8*)(&Ws[c*72 + u*8]) = *(const short8*)(W1s + c*NDm + kc*64 + u*8);
    }
    __syncthreads();
    #pragma unroll
    for (int kb2=0; kb2<2; kb2++){
      short8 af = afs[kc*2 + kb2];
      #pragma unroll
      for (int ct=0; ct<12; ct++){
        short8 bfb = *(const short8*)(&Ws[(ct*16 + lrow)*72 + kb2*32 + quad*8]);
        acc[ct] = __builtin_amdgcn_mfma_f32_16x16x32_bf16(af, bfb, acc[ct], 0,0,0);
      }
    }
  }
  // gelu -> Hs (wave-private rows, no barrier)
  #pragma unroll
  for (int ct=0; ct<12; ct++){
    #pragma unroll
    for (int r=0;r<4;r++){
      Hs[wave*16 + quad*4 + r][ct*16 + lrow] = f2bf(gelu_t(acc[ct][r]));
    }
  }

  // ---- GEMM2: [32,192]@[192,96]; 2 staged chunks of K=96
  const short* W2s = W2t + (size_t)s*NFm*NHm;
  float4v acc2[6];
  #pragma unroll
  for (int i=0;i<6;i++){ acc2[i][0]=0.f; acc2[i][1]=0.f; acc2[i][2]=0.f; acc2[i][3]=0.f; }
  for (int kc2=0; kc2<2; kc2++){
    __syncthreads();                           // prior Ws reads complete
    for (int e = tid; e < 96*12; e += 128){    // 96 cols x 12 short8 units (K=96)
      int c = e / 12, u = e - c*12;
      *(short8*)(&Ws[c*104 + u*8]) = *(const short8*)(W2s + c*NHm + kc2*96 + u*8);
    }
    __syncthreads();
    #pragma unroll
    for (int kb=0; kb<3; kb++){
      short8 af2 = *(const short8*)(&Hs[wave*16 + lrow][(kc2*3 + kb)*32 + quad*8]);
      #pragma unroll
      for (int ct=0; ct<6; ct++){
        short8 bfb = *(const short8*)(&Ws[(ct*16 + lrow)*104 + kb*32 + quad*8]);
        acc2[ct] = __builtin_amdgcn_mfma_f32_16x16x32_bf16(af2, bfb, acc2[ct], 0,0,0);
      }
    }
  }
  // internal -> Is (wave-private)
  #pragma unroll
  for (int ct=0; ct<6; ct++){
    #pragma unroll
    for (int r=0;r<4;r++){
      Is[wave*16 + quad*4 + r][ct*16 + lrow] = f2bf(acc2[ct][r]);
    }
  }

  // ---- epilogue A (verified since R0): pre = dot(internal_row, Wf[s][0:96])
  {
    float pr[4] = {0.f,0.f,0.f,0.f};
    #pragma unroll
    for (int ct=0; ct<6; ct++){
      float wv = Wf[s*2*NFm + ct*16 + lrow];
      #pragma unroll
      for (int r=0;r<4;r++) pr[r] += acc2[ct][r] * wv;
    }
    #pragma unroll
    for (int m=1; m<16; m<<=1){
      #pragma unroll
      for (int r=0;r<4;r++) pr[r] += __shfl_xor(pr[r], m, 64);
    }
    if (lrow == 0){
      #pragma unroll
      for (int r=0;r<4;r++){
        int row = wave*16 + quad*4 + r;
        if (row0 + row < cnt) pre[aids[row]] = pr[r];
      }
    }
  }

  // ---- GEMM3: [32,96]@[96,96]; stage whole Wn once
  const short* Wns = Wnt + (size_t)s*NFm*NFm;
  float4v acc3[6];
  #pragma unroll
  for (int i=0;i<6;i++){ acc3[i][0]=0.f; acc3[i][1]=0.f; acc3[i][2]=0.f; acc3[i][3]=0.f; }
  __syncthreads();                             // GEMM2 Ws reads complete
  for (int e = tid; e < 96*12; e += 128){      // 96 cols x 12 short8 units (K=96)
    int c = e / 12, u = e - c*12;
    *(short8*)(&Ws[c*104 + u*8]) = *(const short8*)(Wns + c*NFm + u*8);
  }
  __syncthreads();
  for (int kb=0; kb<3; kb++){
    short8 af3 = *(const short8*)(&Is[wave*16 + lrow][kb*32 + quad*8]);
    #pragma unroll
    for (int ct=0; ct<6; ct++){
      short8 bfb = *(const short8*)(&Ws[(ct*16 + lrow)*104 + kb*32 + quad*8]);
      acc3[ct] = __builtin_amdgcn_mfma_f32_16x16x32_bf16(af3, bfb, acc3[ct], 0,0,0);
    }
  }

  // ---- epilogue B (LDS-staged, R12-verified): nd4[a][t2] = dot(nbr_row, Wf[t2][F:2F])
  {
    float* NL = (float*)Ws;            // Ws dead after GEMM3 reads (barrier below)
    __syncthreads();                   // all waves done reading Ws
    #pragma unroll
    for (int ct=0; ct<6; ct++){
      #pragma unroll
      for (int r=0;r<4;r++){
        NL[(wave*16 + quad*4 + r)*97 + ct*16 + lrow] = acc3[ct][r]; // 32*97*4=12.4KB
      }
    }
    __syncthreads();
    int row = tid >> 2, t2 = tid & 3;  // 128 threads -> 32 rows x 4
    if (row0 + row < cnt){
      const float* wfp = Wf + t2*2*NFm + NFm;
      const float* nlr = NL + row*97;
      float a4 = 0.f;
      #pragma unroll 8
      for (int j=0;j<NFm;j++) a4 += nlr[j] * wfp[j];
      nd4[(size_t)aids[row]*4 + t2] = a4;
    }
  }
}

// ---------- K-eacc: edge accumulate via full-mrg LDS privatization (R8-verified) ----------
__global__ __launch_bounds__(1024) void k_eacc(const int* __restrict__ ai,
    const float* __restrict__ dist, const float* __restrict__ pref,
    const float* __restrict__ fac, const int* __restrict__ sp,
    const float* __restrict__ nd4, float* __restrict__ part){
  __shared__ float acc[NATOMS];    // 96 KB
  const int t = threadIdx.x, b = blockIdx.x;
  #pragma unroll
  for (int k=0;k<NATOMS/1024;k++) acc[k*1024 + t] = 0.f;   // 24 stores
  __syncthreads();
  const float p = pref[0], fc = fac[0];
  const int base = b*EPB;
  #pragma unroll
  for (int k=0;k<EPB/1024;k++){    // 3 edges/thread, coalesced
    int e = base + k*1024 + t;
    int i0 = ai[e];
    int i1 = ai[NEe + e];
    float d = dist[e];
    int s0 = sp[i0], s1 = sp[i1];
    float4v n1v = *(const float4v*)(nd4 + (size_t)i1*4);
    float4v n0v = *(const float4v*)(nd4 + (size_t)i0*4);
    float x = (CUTOFF_ - d) * (1.0f/CUTOFF_);
    x = fminf(fmaxf(x, 0.f), 1.f);
    float sc = x*x*x*(x*(6.f*x - 15.f) + 10.f);
    float w = p*p * expf(-fc*fc*d) * sc;
    float a1 = (s0 < 2) ? ((s0 == 0) ? n1v[0] : n1v[1]) : ((s0 == 2) ? n1v[2] : n1v[3]);
    float a0 = (s1 < 2) ? ((s1 == 0) ? n0v[0] : n0v[1]) : ((s1 == 2) ? n0v[2] : n0v[3]);
    atomicAdd(&acc[i0], w * a1);
    atomicAdd(&acc[i1], w * a0);
  }
  __syncthreads();
  float* dst = part + (size_t)b*NATOMS;
  for (int k=t; k<NATOMS/4; k+=1024){            // 6 x float4 stores, coalesced
    *(float4v*)(dst + k*4) = *(const float4v*)(&acc[k*4]);
  }
}

// ---------- per-molecule: 256-partial reduce + charge redistribution (R8-verified) ----------
__global__ __launch_bounds__(128) void k_final(const float* __restrict__ pre,
    const float* __restrict__ part, const int* __restrict__ sp,
    const float* __restrict__ tc, float* __restrict__ out){
  __shared__ float red[128];
  int mol = blockIdx.x, t = threadIdx.x;
  float pch = 0.f; int s = 0;
  if (t < NAm){
    int a = mol*NAm + t;
    s = sp[a];
    float m = 0.f;
    #pragma unroll 8
    for (int b=0; b<PBLK; b++) m += part[(size_t)b*NATOMS + a];
    pch = pre[a] + m;
  }
  red[t] = (t < NAm) ? pch : 0.f;
  __syncthreads();
  for (int o=64; o>0; o>>=1){
    if (t < o) red[t] += red[t + o];
    __syncthreads();
  }
  float sum = red[0];
  if (t < NAm){
    out[mol*NAm + t] = (float)s;                       // species as float
    out[NATOMS + mol*NAm + t] = pch + (tc[mol] - sum) * (1.0f/96.0f);  // charges
    out[2*NATOMS + mol*NAm + t] = pch;                 // precharges
  }
}

extern "C" void kernel_launch(void* const* d_in, const int* in_sizes, int n_in,
                              void* d_out, int out_size, void* d_ws, size_t ws_size,
                              hipStream_t stream) {
  const int*   species = (const int*)  d_in[0];
  const float* X       = (const float*)d_in[1];
  const int*   ai      = (const int*)  d_in[2];
  const float* dist    = (const float*)d_in[3];
  const float* tc      = (const float*)d_in[4];
  const float* W1      = (const float*)d_in[5];
  const float* W2      = (const float*)d_in[6];
  const float* Wn      = (const float*)d_in[7];
  const float* Wf      = (const float*)d_in[8];
  const float* pref    = (const float*)d_in[9];
  const float* fac     = (const float*)d_in[10];
  float* out = (float*)d_out;

  char* w = (char*)d_ws;
  auto alloc = [&](size_t bytes)->char*{
    char* p = w; w += (bytes + 255) & ~(size_t)255; return p;
  };
  int*   Pcnt  = (int*)  alloc((size_t)HBLK*NSm*4);
  int*   sps   = (int*)  alloc(64);
  int*   order = (int*)  alloc((size_t)NATOMS*4);
  float* nd4   = (float*)alloc((size_t)NATOMS*4*4);
  float* pre   = (float*)alloc((size_t)NATOMS*4);
  float* part  = (float*)alloc((size_t)PBLK*NATOMS*4);   // 25.2 MB
  short* W1t   = (short*)alloc((size_t)W1N*2);
  short* W2t   = (short*)alloc((size_t)W2N*2);
  short* Wnt   = (short*)alloc((size_t)WNN*2);

  k_prep<<<WBLK + HBLK, 256, 0, stream>>>(W1, W2, Wn, species, W1t, W2t, Wnt, Pcnt);
  k_order<<<HBLK, 256, 0, stream>>>(species, Pcnt, sps, order);
  dim3 g((NATOMS + MROWS - 1)/MROWS, NSm);   // 768 x 4, early-exit per species
  k_mlp<<<g, 128, 0, stream>>>(X, order, sps, W1t, W2t, Wnt, Wf, pre, nd4);
  k_eacc<<<PBLK, 1024, 0, stream>>>(ai, dist, pref, fac, species, nd4, part);
  k_final<<<NBm, 128, 0, stream>>>(pre, part, species, tc, out);
}

// Round 23
// 189.223 us; speedup vs baseline: 1.0598x; 1.0598x over previous
//
#include <hip/hip_runtime.h>
#include <cstdint>
#include <cstddef>

#define NBm 256
#define NAm 96
#define NDm 384
#define NHm 192
#define NFm 96
#define NSm 4
#define NATOMS (NBm*NAm)      /* 24576 */
#define NEe (NATOMS*32)       /* 786432 */
#define CUTOFF_ 5.2f
#define PBLK 256              /* edge-accum blocks = partial copies */
#define EPB (NEe/PBLK)        /* 3072 edges per block */
#define HBLK 96               /* NATOMS/256 hist blocks */
#define MROWS 48              /* k_mlp rows per block (3 waves x 16) */
#define MTHR 192              /* k_mlp threads */

typedef __attribute__((ext_vector_type(8))) short short8;
typedef __attribute__((ext_vector_type(4))) float float4v;

__device__ __forceinline__ short f2bf(float f){
  union { float f; unsigned u; } v; v.f = f;
  unsigned r = v.u + 0x7FFFu + ((v.u >> 16) & 1u);
  return (short)(r >> 16);
}

// jax.nn.gelu default: tanh approximation
__device__ __forceinline__ float gelu_t(float x){
  float u = 0.7978845608028654f * (x + 0.044715f * x*x*x);
  float e = __expf(-2.0f * fabsf(u));
  float t = (1.0f - e) / (1.0f + e);
  t = (u >= 0.f) ? t : -t;
  return 0.5f * x * (1.0f + t);
}

// ---------- K1: weight prep + per-block species histogram (R14-verified) ----------
#define W1N (NSm*NDm*NHm)   /* 294912 */
#define W2N (NSm*NHm*NFm)   /* 73728 */
#define WNN (NSm*NFm*NFm)   /* 36864 */
#define WTOT (W1N+W2N+WNN)  /* 405504 */
#define WBLK (WTOT/256)     /* 1584 */
// grid = WBLK + HBLK = 1680
__global__ __launch_bounds__(256) void k_prep(
    const float* __restrict__ W1, const float* __restrict__ W2,
    const float* __restrict__ Wn, const int* __restrict__ sp,
    short* __restrict__ W1t, short* __restrict__ W2t, short* __restrict__ Wnt,
    int* __restrict__ Pcnt){
  int b = blockIdx.x;
  if (b < WBLK){
    int idx = b*256 + threadIdx.x;
    if (idx < W1N){
      int s = idx / (NDm*NHm); int rem = idx - s*NDm*NHm;
      int k = rem / NHm, c = rem - k*NHm;
      W1t[(s*NHm + c)*NDm + k] = f2bf(W1[idx]);
    } else if (idx < W1N + W2N){
      int j = idx - W1N;
      int s = j / (NHm*NFm); int rem = j - s*NHm*NFm;
      int k = rem / NFm, c = rem - k*NFm;
      W2t[(s*NFm + c)*NHm + k] = f2bf(W2[j]);
    } else {
      int j = idx - W1N - W2N;
      int s = j / (NFm*NFm); int rem = j - s*NFm*NFm;
      int k = rem / NFm, c = rem - k*NFm;
      Wnt[(s*NFm + c)*NFm + k] = f2bf(Wn[j]);
    }
  } else {
    // per-block species histogram; LDS atomics only, no pre-zero needed
    __shared__ int h[NSm];
    int t = threadIdx.x;
    if (t < NSm) h[t] = 0;
    __syncthreads();
    int i = (b - WBLK)*256 + t;
    atomicAdd(&h[sp[i]], 1);
    __syncthreads();
    if (t < NSm) Pcnt[(b - WBLK)*NSm + t] = h[t];
  }
}

// ---------- K2: redundant-scan ordering (R14-verified) ----------
__global__ __launch_bounds__(256) void k_order(const int* __restrict__ sp,
    const int* __restrict__ Pcnt, int* __restrict__ sps, int* __restrict__ order){
  __shared__ int P[HBLK][NSm];
  __shared__ int stot[NSm], spre[NSm], sscan[NSm+1];
  __shared__ int base[NSm], h[NSm];
  int t = threadIdx.x, b = blockIdx.x;
  if (t < HBLK){
    #pragma unroll
    for (int j=0;j<NSm;j++) P[t][j] = Pcnt[t*NSm + j];
  }
  if (t < NSm) h[t] = 0;
  __syncthreads();
  if (t < NSm){
    int tot = 0, pr = 0;
    for (int bb=0; bb<HBLK; bb++){
      if (bb == b) pr = tot;
      tot += P[bb][t];
    }
    stot[t] = tot; spre[t] = pr;
  }
  __syncthreads();
  if (t == 0){
    int r = 0;
    #pragma unroll
    for (int s2=0;s2<NSm;s2++){ sscan[s2] = r; r += stot[s2]; }
    sscan[NSm] = r;
    if (b == 0){
      #pragma unroll
      for (int s2=0;s2<=NSm;s2++) sps[s2] = sscan[s2];
    }
  }
  __syncthreads();
  if (t < NSm) base[t] = sscan[t] + spre[t];
  __syncthreads();
  int i = b*256 + t;
  int s = sp[i];
  int lr = atomicAdd(&h[s], 1);
  order[base[s] + lr] = i;
}

// ---------- fused MLP: 48-row tiles, exactly 2 balanced blocks/CU ----------
// Sweep evidence: 96-row/1-deep=85us, 32-row/3-deep=72us, 64-row/1.5-deep=41.8us.
// 2-deep co-residency (independent barrier groups overlap) is the proven lever;
// R14's imbalance (2-block CUs do 128 rows, 1-block CUs idle after 64) is the
// remaining waste. 48-row x 512 blocks = exactly 2/CU, balanced (96 rows/CU).
// Per-wave dataflow byte-identical to R14 (16 rows x 12 ct, same K chunking);
// only stage-loop strides change (192). LDS 67.7KB -> 2 blocks/CU.
__global__ __launch_bounds__(MTHR) void k_mlp(
    const float* __restrict__ X, const int* __restrict__ order,
    const int* __restrict__ sps,
    const short* __restrict__ W1t, const short* __restrict__ W2t,
    const short* __restrict__ Wnt, const float* __restrict__ Wf,
    float* __restrict__ pre, float* __restrict__ nd4){
  const int s = blockIdx.y;
  const int s0 = sps[s];
  const int cnt = sps[s+1] - s0;
  const int row0 = blockIdx.x * MROWS;
  if (row0 >= cnt) return;

  __shared__ short Hs[MROWS][200]; // 19.2 KB
  __shared__ short Is[MROWS][104]; // 10.0 KB
  __shared__ short Ws[19968];      // 39.9 KB staging buffer (aliased as NL below)
  __shared__ int aids[MROWS];

  const int tid = threadIdx.x;
  if (tid < MROWS){
    int r = row0 + tid;
    aids[tid] = order[s0 + ((r < cnt) ? r : 0)];
  }
  __syncthreads();

  const int wave = tid >> 6, lane = tid & 63;   // wave 0..2
  const int lrow = lane & 15, quad = lane >> 4;
  const int arow = wave*16 + lrow;
  const float* xrow = X + (size_t)aids[arow]*NDm + quad*8;

  // preload & convert all A fragments (GEMM1) up front
  short8 afs[12];
  #pragma unroll
  for (int kb=0; kb<12; kb++){
    const float* p = xrow + kb*32;
    #pragma unroll
    for (int j=0;j<8;j++) afs[kb][j] = f2bf(p[j]);
  }

  // ---- GEMM1: [48,384]@[384,192]; 4 staged chunks of K=96
  const short* W1s = W1t + (size_t)s*NHm*NDm;
  float4v acc[12];
  #pragma unroll
  for (int i=0;i<12;i++){ acc[i][0]=0.f; acc[i][1]=0.f; acc[i][2]=0.f; acc[i][3]=0.f; }
  for (int kc=0; kc<4; kc++){
    __syncthreads();
    for (int e = tid; e < 192*12; e += MTHR){  // 192 cols x 12 short8 units
      int c = e / 12, u = e - c*12;
      *(short8*)(&Ws[c*104 + u*8]) = *(const short8*)(W1s + c*NDm + kc*96 + u*8);
    }
    __syncthreads();
    #pragma unroll
    for (int kb3=0; kb3<3; kb3++){
      short8 af = afs[kc*3 + kb3];
      #pragma unroll
      for (int ct=0; ct<12; ct++){
        short8 bfb = *(const short8*)(&Ws[(ct*16 + lrow)*104 + kb3*32 + quad*8]);
        acc[ct] = __builtin_amdgcn_mfma_f32_16x16x32_bf16(af, bfb, acc[ct], 0,0,0);
      }
    }
  }
  // gelu -> Hs (wave-private rows, no barrier)
  #pragma unroll
  for (int ct=0; ct<12; ct++){
    #pragma unroll
    for (int r=0;r<4;r++){
      Hs[wave*16 + quad*4 + r][ct*16 + lrow] = f2bf(gelu_t(acc[ct][r]));
    }
  }

  // ---- GEMM2: [48,192]@[192,96]; stage whole W2 once
  const short* W2s = W2t + (size_t)s*NFm*NHm;
  float4v acc2[6];
  #pragma unroll
  for (int i=0;i<6;i++){ acc2[i][0]=0.f; acc2[i][1]=0.f; acc2[i][2]=0.f; acc2[i][3]=0.f; }
  __syncthreads();
  for (int e = tid; e < 96*24; e += MTHR){     // 96 cols x 24 short8 units (K=192)
    int c = e / 24, u = e - c*24;
    *(short8*)(&Ws[c*200 + u*8]) = *(const short8*)(W2s + c*NHm + u*8);
  }
  __syncthreads();
  for (int kb=0; kb<6; kb++){
    short8 af2 = *(const short8*)(&Hs[wave*16 + lrow][kb*32 + quad*8]);
    #pragma unroll
    for (int ct=0; ct<6; ct++){
      short8 bfb = *(const short8*)(&Ws[(ct*16 + lrow)*200 + kb*32 + quad*8]);
      acc2[ct] = __builtin_amdgcn_mfma_f32_16x16x32_bf16(af2, bfb, acc2[ct], 0,0,0);
    }
  }
  // internal -> Is (wave-private)
  #pragma unroll
  for (int ct=0; ct<6; ct++){
    #pragma unroll
    for (int r=0;r<4;r++){
      Is[wave*16 + quad*4 + r][ct*16 + lrow] = f2bf(acc2[ct][r]);
    }
  }

  // ---- epilogue A (verified since R0): pre = dot(internal_row, Wf[s][0:96])
  {
    float pr[4] = {0.f,0.f,0.f,0.f};
    #pragma unroll
    for (int ct=0; ct<6; ct++){
      float wv = Wf[s*2*NFm + ct*16 + lrow];
      #pragma unroll
      for (int r=0;r<4;r++) pr[r] += acc2[ct][r] * wv;
    }
    #pragma unroll
    for (int m=1; m<16; m<<=1){
      #pragma unroll
      for (int r=0;r<4;r++) pr[r] += __shfl_xor(pr[r], m, 64);
    }
    if (lrow == 0){
      #pragma unroll
      for (int r=0;r<4;r++){
        int row = wave*16 + quad*4 + r;
        if (row0 + row < cnt) pre[aids[row]] = pr[r];
      }
    }
  }

  // ---- GEMM3: [48,96]@[96,96]; stage whole Wn once
  const short* Wns = Wnt + (size_t)s*NFm*NFm;
  float4v acc3[6];
  #pragma unroll
  for (int i=0;i<6;i++){ acc3[i][0]=0.f; acc3[i][1]=0.f; acc3[i][2]=0.f; acc3[i][3]=0.f; }
  __syncthreads();
  for (int e = tid; e < 96*12; e += MTHR){     // 96 cols x 12 short8 units (K=96)
    int c = e / 12, u = e - c*12;
    *(short8*)(&Ws[c*104 + u*8]) = *(const short8*)(Wns + c*NFm + u*8);
  }
  __syncthreads();
  for (int kb=0; kb<3; kb++){
    short8 af3 = *(const short8*)(&Is[wave*16 + lrow][kb*32 + quad*8]);
    #pragma unroll
    for (int ct=0; ct<6; ct++){
      short8 bfb = *(const short8*)(&Ws[(ct*16 + lrow)*104 + kb*32 + quad*8]);
      acc3[ct] = __builtin_amdgcn_mfma_f32_16x16x32_bf16(af3, bfb, acc3[ct], 0,0,0);
    }
  }

  // ---- epilogue B (LDS-staged, R12-verified): nd4[a][t2] = dot(nbr_row, Wf[t2][F:2F])
  {
    float* NL = (float*)Ws;            // Ws dead after GEMM3 reads (barrier below)
    __syncthreads();                   // all waves done reading Ws
    #pragma unroll
    for (int ct=0; ct<6; ct++){
      #pragma unroll
      for (int r=0;r<4;r++){
        NL[(wave*16 + quad*4 + r)*97 + ct*16 + lrow] = acc3[ct][r]; // 48*97*4=18.6KB
      }
    }
    __syncthreads();
    int row = tid >> 2, t2 = tid & 3;  // 192 threads -> 48 rows x 4
    if (row0 + row < cnt){
      const float* wfp = Wf + t2*2*NFm + NFm;
      const float* nlr = NL + row*97;
      float a4 = 0.f;
      #pragma unroll 8
      for (int j=0;j<NFm;j++) a4 += nlr[j] * wfp[j];
      nd4[(size_t)aids[row]*4 + t2] = a4;
    }
  }
}

// ---------- K-eacc: edge accumulate via full-mrg LDS privatization (R8-verified) ----------
__global__ __launch_bounds__(1024) void k_eacc(const int* __restrict__ ai,
    const float* __restrict__ dist, const float* __restrict__ pref,
    const float* __restrict__ fac, const int* __restrict__ sp,
    const float* __restrict__ nd4, float* __restrict__ part){
  __shared__ float acc[NATOMS];    // 96 KB
  const int t = threadIdx.x, b = blockIdx.x;
  #pragma unroll
  for (int k=0;k<NATOMS/1024;k++) acc[k*1024 + t] = 0.f;   // 24 stores
  __syncthreads();
  const float p = pref[0], fc = fac[0];
  const int base = b*EPB;
  #pragma unroll
  for (int k=0;k<EPB/1024;k++){    // 3 edges/thread, coalesced
    int e = base + k*1024 + t;
    int i0 = ai[e];
    int i1 = ai[NEe + e];
    float d = dist[e];
    int s0 = sp[i0], s1 = sp[i1];
    float4v n1v = *(const float4v*)(nd4 + (size_t)i1*4);
    float4v n0v = *(const float4v*)(nd4 + (size_t)i0*4);
    float x = (CUTOFF_ - d) * (1.0f/CUTOFF_);
    x = fminf(fmaxf(x, 0.f), 1.f);
    float sc = x*x*x*(x*(6.f*x - 15.f) + 10.f);
    float w = p*p * expf(-fc*fc*d) * sc;
    float a1 = (s0 < 2) ? ((s0 == 0) ? n1v[0] : n1v[1]) : ((s0 == 2) ? n1v[2] : n1v[3]);
    float a0 = (s1 < 2) ? ((s1 == 0) ? n0v[0] : n0v[1]) : ((s1 == 2) ? n0v[2] : n0v[3]);
    atomicAdd(&acc[i0], w * a1);
    atomicAdd(&acc[i1], w * a0);
  }
  __syncthreads();
  float* dst = part + (size_t)b*NATOMS;
  for (int k=t; k<NATOMS/4; k+=1024){            // 6 x float4 stores, coalesced
    *(float4v*)(dst + k*4) = *(const float4v*)(&acc[k*4]);
  }
}

// ---------- per-molecule: 256-partial reduce + charge redistribution (R8-verified) ----------
__global__ __launch_bounds__(128) void k_final(const float* __restrict__ pre,
    const float* __restrict__ part, const int* __restrict__ sp,
    const float* __restrict__ tc, float* __restrict__ out){
  __shared__ float red[128];
  int mol = blockIdx.x, t = threadIdx.x;
  float pch = 0.f; int s = 0;
  if (t < NAm){
    int a = mol*NAm + t;
    s = sp[a];
    float m = 0.f;
    #pragma unroll 8
    for (int b=0; b<PBLK; b++) m += part[(size_t)b*NATOMS + a];
    pch = pre[a] + m;
  }
  red[t] = (t < NAm) ? pch : 0.f;
  __syncthreads();
  for (int o=64; o>0; o>>=1){
    if (t < o) red[t] += red[t + o];
    __syncthreads();
  }
  float sum = red[0];
  if (t < NAm){
    out[mol*NAm + t] = (float)s;                       // species as float
    out[NATOMS + mol*NAm + t] = pch + (tc[mol] - sum) * (1.0f/96.0f);  // charges
    out[2*NATOMS + mol*NAm + t] = pch;                 // precharges
  }
}

extern "C" void kernel_launch(void* const* d_in, const int* in_sizes, int n_in,
                              void* d_out, int out_size, void* d_ws, size_t ws_size,
                              hipStream_t stream) {
  const int*   species = (const int*)  d_in[0];
  const float* X       = (const float*)d_in[1];
  const int*   ai      = (const int*)  d_in[2];
  const float* dist    = (const float*)d_in[3];
  const float* tc      = (const float*)d_in[4];
  const float* W1      = (const float*)d_in[5];
  const float* W2      = (const float*)d_in[6];
  const float* Wn      = (const float*)d_in[7];
  const float* Wf      = (const float*)d_in[8];
  const float* pref    = (const float*)d_in[9];
  const float* fac     = (const float*)d_in[10];
  float* out = (float*)d_out;

  char* w = (char*)d_ws;
  auto alloc = [&](size_t bytes)->char*{
    char* p = w; w += (bytes + 255) & ~(size_t)255; return p;
  };
  int*   Pcnt  = (int*)  alloc((size_t)HBLK*NSm*4);
  int*   sps   = (int*)  alloc(64);
  int*   order = (int*)  alloc((size_t)NATOMS*4);
  float* nd4   = (float*)alloc((size_t)NATOMS*4*4);
  float* pre   = (float*)alloc((size_t)NATOMS*4);
  float* part  = (float*)alloc((size_t)PBLK*NATOMS*4);   // 25.2 MB
  short* W1t   = (short*)alloc((size_t)W1N*2);
  short* W2t   = (short*)alloc((size_t)W2N*2);
  short* Wnt   = (short*)alloc((size_t)WNN*2);

  k_prep<<<WBLK + HBLK, 256, 0, stream>>>(W1, W2, Wn, species, W1t, W2t, Wnt, Pcnt);
  k_order<<<HBLK, 256, 0, stream>>>(species, Pcnt, sps, order);
  dim3 g((NATOMS + MROWS - 1)/MROWS, NSm);   // 512 x 4, early-exit per species
  k_mlp<<<g, MTHR, 0, stream>>>(X, order, sps, W1t, W2t, Wnt, Wf, pre, nd4);
  k_eacc<<<PBLK, 1024, 0, stream>>>(ai, dist, pref, fac, species, nd4, part);
  k_final<<<NBm, 128, 0, stream>>>(pre, part, species, tc, out);
}